// Round 3
// baseline (109.457 us; speedup 1.0000x reference)
//
#include <hip/hip_runtime.h>
#include <hip/hip_bf16.h>
#include <math.h>

#define LRELU_ALPHA 0.2f

typedef __attribute__((ext_vector_type(8))) short bf16x8;
typedef __attribute__((ext_vector_type(4))) float f32x4;

__device__ __forceinline__ unsigned short f2bf(float f) {
    union { float f; unsigned u; } v; v.f = f;
    unsigned r = v.u + 0x7fffu + ((v.u >> 16) & 1u);
    return (unsigned short)(r >> 16);
}
__device__ __forceinline__ float bf2f(unsigned short s) {
    union { unsigned u; float f; } v; v.u = ((unsigned)s) << 16;
    return v.f;
}

// Kernel 0: Wt[h][n][k], n<64: bf16(W[h][k][n]); n=64+q: bf16(sum_o W[h][k][o]*a_q[o])
// where a_q = {a_pos[:64], a_pos[64:], a_neg[:64], a_neg[64:]}.  H*80*64 elems.
__global__ void wtrans_kernel(const float* __restrict__ W,
                              const float* __restrict__ a_pos, const float* __restrict__ a_neg,
                              unsigned short* __restrict__ Wt, int H) {
    int t = blockIdx.x * blockDim.x + threadIdx.x;
    if (t >= H * 80 * 64) return;
    int k = t & 63, n = (t >> 6) % 80, h = t / (80 * 64);
    float v;
    if (n < 64) {
        v = W[(size_t)h * 4096 + k * 64 + n];
    } else {
        int q = n - 64;
        const float* a  = (q < 2 ? a_pos : a_neg) + (size_t)h * 128 + (q & 1) * 64;
        const float* wr = W + (size_t)h * 4096 + k * 64;
        v = 0.f;
        for (int o = 0; o < 64; ++o) v = fmaf(wr[o], a[o], v);
    }
    Wt[t] = f2bf(v);
}

// Kernel 1: MFMA Wh = gather(nf)[U,64] @ W[h][64,64] -> WhB bf16; the 5th n-tile
// (cols 64..67) directly yields the 4 score dots per (h,u) -> scf.
__global__ __launch_bounds__(256) void wh_mfma_kernel(
    const float* __restrict__ nf, const unsigned short* __restrict__ Wt,
    const int* __restrict__ unique_nodes,
    unsigned short* __restrict__ WhB, float* __restrict__ scf, int U, int H)
{
    const int wave = threadIdx.x >> 6;
    const int lane = threadIdx.x & 63;
    const int grp  = lane >> 4;   // k block
    const int r    = lane & 15;   // row in A-tile / col in B-tile
    const long u0  = ((long)blockIdx.x * 4 + wave) * 16;
    if (u0 >= U) return;

    const long ur = (u0 + r < U) ? (u0 + r) : (long)(U - 1);
    const float* erow = nf + (size_t)unique_nodes[ur] * 64 + grp * 8;
    bf16x8 a0, a1;
#pragma unroll
    for (int i = 0; i < 8; ++i) {
        a0[i] = (short)f2bf(erow[i]);        // k = grp*8 + i
        a1[i] = (short)f2bf(erow[32 + i]);   // k = 32 + grp*8 + i
    }

    for (int h = 0; h < H; ++h) {
        f32x4 acc[5];
#pragma unroll
        for (int nt = 0; nt < 5; ++nt) {
            acc[nt] = (f32x4)(0.f);
            const unsigned short* wp = Wt + (((size_t)h * 80 + nt * 16 + r) * 64 + grp * 8);
            bf16x8 b0 = *(const bf16x8*)wp;        // same k mapping as A
            bf16x8 b1 = *(const bf16x8*)(wp + 32);
            acc[nt] = __builtin_amdgcn_mfma_f32_16x16x32_bf16(a0, b0, acc[nt], 0, 0, 0);
            acc[nt] = __builtin_amdgcn_mfma_f32_16x16x32_bf16(a1, b1, acc[nt], 0, 0, 0);
        }
        // C/D layout: col = nt*16 + r, row(u-offset) = grp*4 + j
#pragma unroll
        for (int j = 0; j < 4; ++j) {
            const long u = u0 + grp * 4 + j;
            if (u < U) {
#pragma unroll
                for (int nt = 0; nt < 4; ++nt)
                    WhB[((size_t)h * U + u) * 64 + nt * 16 + r] = f2bf(acc[nt][j]);
                if (r < 4) scf[(((size_t)h * U + u) << 2) + r] = acc[4][j];
            }
        }
    }
}

// Kernel 2: one wave per (row, head). Head pinned to an XCD pair via bid%8 so the
// head's 7.2MB (WhB slab + scores) lives in the pair's 8MB L2.
template <int DP, int DN>
__global__ __launch_bounds__(256) void agg_kernel(
    const int* __restrict__ row_unique,
    const int* __restrict__ pos_col, const int* __restrict__ neg_col,
    const unsigned short* __restrict__ WhB, const float4* __restrict__ sc,
    float* __restrict__ out, int N, int U, int rDP, int rDN, int H, int pinned)
{
    const int DEGP = DP > 0 ? DP : rDP;
    const int DEGN = DN > 0 ? DN : rDN;
    const int NE   = DEGP + 1 + DEGN;

    const int wave = threadIdx.x >> 6;
    const int lane = threadIdx.x & 63;

    int i, h;
    if (pinned) {
        const int xcd = blockIdx.x & 7;
        h = xcd >> 1;                                        // 2 XCDs per head
        const int rg = ((blockIdx.x >> 3) << 1) | (blockIdx.x & 1);
        i = rg * 4 + wave;
    } else {
        const long j = (long)blockIdx.x * 4 + wave;
        i = (int)(j % N);
        h = (int)(j / N);
        if (h >= H) return;
    }
    if (i >= N) return;

    const float4* sch = sc + (size_t)h * U;
    const float4 scd = sch[row_unique[i]];   // .x = pos_dst, .z = neg_dst

    int col = 0;
    float score = -INFINITY;
    if (lane < NE) {
        if (lane < DEGP)       col = pos_col[(size_t)i * DEGP + lane];
        else if (lane == DEGP) col = pos_col[(size_t)N * DEGP + i];  // self edge
        else                   col = neg_col[(size_t)i * DEGN + (lane - DEGP - 1)];
        const float4 scs = sch[col];         // .y = pos_src, .w = neg_src
        const float raw = (lane <= DEGP) ? (scd.x + scs.y) : (scd.z + scs.w);
        score = (raw > 0.f) ? raw : LRELU_ALPHA * raw;
    }
    float m = score;
#pragma unroll
    for (int off = 32; off; off >>= 1) m = fmaxf(m, __shfl_xor(m, off, 64));
    const float ex = (lane < NE) ? __expf(score - m) : 0.f;
    float ssum = ex;
#pragma unroll
    for (int off = 32; off; off >>= 1) ssum += __shfl_xor(ssum, off, 64);
    const float att = ex / ssum;

    const unsigned short* wh = WhB + (size_t)h * U * 64;
    float acc = 0.f;
#pragma unroll
    for (int e = 0; e < NE; ++e) {
        const int   c = __shfl(col, e, 64);
        const float a = __shfl(att, e, 64);
        acc = fmaf(a, bf2f(wh[(size_t)c * 64 + lane]), acc);
    }
    out[(size_t)i * (H * 64) + h * 64 + lane] = fmaxf(acc, 0.f);
}

// Kernel 3: edge_out = edge_embedding @ edge_transform  ([ET,64] @ [64,64])
__global__ void edge_kernel(const float* __restrict__ ee, const float* __restrict__ et,
                            float* __restrict__ out, int ET)
{
    const int t = blockIdx.x * blockDim.x + threadIdx.x;
    const int e = t >> 6, o = t & 63;
    if (e >= ET) return;
    float acc = 0.f;
#pragma unroll
    for (int k = 0; k < 64; ++k)
        acc = fmaf(ee[e * 64 + k], et[k * 64 + o], acc);
    out[t] = acc;
}

extern "C" void kernel_launch(void* const* d_in, const int* in_sizes, int n_in,
                              void* d_out, int out_size, void* d_ws, size_t ws_size,
                              hipStream_t stream) {
    const float* nf     = (const float*)d_in[0];
    const float* W      = (const float*)d_in[1];
    const float* a_pos  = (const float*)d_in[2];
    const float* a_neg  = (const float*)d_in[3];
    const float* ee     = (const float*)d_in[4];
    const float* et     = (const float*)d_in[5];
    const int* unique_nodes = (const int*)d_in[6];
    const int* row_unique   = (const int*)d_in[7];
    const int* pos_col  = (const int*)d_in[9];
    const int* neg_col  = (const int*)d_in[11];

    const int U    = in_sizes[6];
    const int N    = in_sizes[7];
    const int Epos = in_sizes[8];
    const int Eneg = in_sizes[10];
    const int H    = in_sizes[1] / (64 * 64);   // W is [H,64,64]
    const int DEGN = Eneg / N;                  // 16
    const int DEGP = Epos / N - 1;              // 16 (self edges appended)
    const int ET   = in_sizes[4] / 64;          // 32 edge types

    unsigned short* WhB = (unsigned short*)d_ws;
    const size_t whBytes = (((size_t)H * U * 64 * sizeof(unsigned short)) + 255) & ~(size_t)255;
    float* scf = (float*)((char*)d_ws + whBytes);
    const size_t scBytes = (((size_t)H * U * 4 * sizeof(float)) + 255) & ~(size_t)255;
    unsigned short* Wt = (unsigned short*)((char*)d_ws + whBytes + scBytes);
    const float4* sc = (const float4*)scf;
    float* out = (float*)d_out;

    const int WT = H * 80 * 64;
    wtrans_kernel<<<(WT + 255) / 256, 256, 0, stream>>>(W, a_pos, a_neg, Wt, H);

    const int nwaves = (U + 15) / 16;
    wh_mfma_kernel<<<(nwaves + 3) / 4, 256, 0, stream>>>(nf, Wt, unique_nodes, WhB, scf, U, H);

    // head-pinned mapping needs H==4, N%4==0, and block count divisible by 8
    const long NBp = (long)N * H / 4;
    const int pinned = (H == 4 && (N % 4) == 0 && (NBp % 8) == 0) ? 1 : 0;
    const long NB = pinned ? NBp : ((long)N * H + 3) / 4;
    if (DEGP == 16 && DEGN == 16)
        agg_kernel<16, 16><<<NB, 256, 0, stream>>>(row_unique, pos_col, neg_col, WhB, sc,
                                                   out, N, U, DEGP, DEGN, H, pinned);
    else
        agg_kernel<0, 0><<<NB, 256, 0, stream>>>(row_unique, pos_col, neg_col, WhB, sc,
                                                 out, N, U, DEGP, DEGN, H, pinned);

    edge_kernel<<<(ET * 64 + 255) / 256, 256, 0, stream>>>(ee, et, out + (size_t)N * H * 64, ET);
}

// Round 4
// 79.353 us; speedup vs baseline: 1.3794x; 1.3794x over previous
//
#include <hip/hip_runtime.h>
#include <hip/hip_bf16.h>
#include <math.h>

#define LRELU_ALPHA 0.2f

typedef __attribute__((ext_vector_type(8))) short bf16x8;
typedef __attribute__((ext_vector_type(4))) float f32x4;

__device__ __forceinline__ unsigned short f2bf(float f) {
    union { float f; unsigned u; } v; v.f = f;
    unsigned r = v.u + 0x7fffu + ((v.u >> 16) & 1u);
    return (unsigned short)(r >> 16);
}

// Kernel 0 (prep): Wt[h][n][k] = bf16(W[h][k][n]) for n<64;
// n=64+q: bf16(sum_o W[h][k][o]*a_q[o]), a_q = {ap[:64], ap[64:], an[:64], an[64:]}.
// Tail blocks: edge_out = ee @ et.
__global__ void prep_kernel(const float* __restrict__ W,
                            const float* __restrict__ a_pos, const float* __restrict__ a_neg,
                            const float* __restrict__ ee, const float* __restrict__ et,
                            unsigned short* __restrict__ Wt, float* __restrict__ edge_out,
                            int H, int ET) {
    const int WTE = H * 80 * 64;
    int t = blockIdx.x * blockDim.x + threadIdx.x;
    if (t < WTE) {
        int k = t & 63, n = (t >> 6) % 80, h = t / (80 * 64);
        float v;
        if (n < 64) {
            v = W[(size_t)h * 4096 + k * 64 + n];
        } else {
            int q = n - 64;
            const float* a  = (q < 2 ? a_pos : a_neg) + (size_t)h * 128 + (q & 1) * 64;
            const float* wr = W + (size_t)h * 4096 + k * 64;
            v = 0.f;
            for (int o = 0; o < 64; ++o) v = fmaf(wr[o], a[o], v);
        }
        Wt[t] = f2bf(v);
    } else {
        int s = t - WTE;
        if (s < ET * 64) {
            int e = s >> 6, o = s & 63;
            float acc = 0.f;
#pragma unroll
            for (int k = 0; k < 64; ++k)
                acc = fmaf(ee[e * 64 + k], et[k * 64 + o], acc);
            edge_out[s] = acc;
        }
    }
}

// Kernel 1: MFMA Wh = gather(nf)[U,64] @ W[h][64,64] -> WhB bf16; 5th n-tile gives
// the 4 score dots per (h,u) -> scf (float4 per (h,u), layout [h][u]).
__global__ __launch_bounds__(256) void wh_mfma_kernel(
    const float* __restrict__ nf, const unsigned short* __restrict__ Wt,
    const int* __restrict__ unique_nodes,
    unsigned short* __restrict__ WhB, float* __restrict__ scf, int U, int H)
{
    const int wave = threadIdx.x >> 6;
    const int lane = threadIdx.x & 63;
    const int grp  = lane >> 4;   // k block
    const int r    = lane & 15;   // row in A-tile / col in B-tile
    const long u0  = ((long)blockIdx.x * 4 + wave) * 16;
    if (u0 >= U) return;

    const long ur = (u0 + r < U) ? (u0 + r) : (long)(U - 1);
    const float* erow = nf + (size_t)unique_nodes[ur] * 64 + grp * 8;
    const float4 e0 = *(const float4*)(erow);
    const float4 e1 = *(const float4*)(erow + 4);
    const float4 e2 = *(const float4*)(erow + 32);
    const float4 e3 = *(const float4*)(erow + 36);
    bf16x8 a0, a1;
    a0[0] = (short)f2bf(e0.x); a0[1] = (short)f2bf(e0.y);
    a0[2] = (short)f2bf(e0.z); a0[3] = (short)f2bf(e0.w);
    a0[4] = (short)f2bf(e1.x); a0[5] = (short)f2bf(e1.y);
    a0[6] = (short)f2bf(e1.z); a0[7] = (short)f2bf(e1.w);
    a1[0] = (short)f2bf(e2.x); a1[1] = (short)f2bf(e2.y);
    a1[2] = (short)f2bf(e2.z); a1[3] = (short)f2bf(e2.w);
    a1[4] = (short)f2bf(e3.x); a1[5] = (short)f2bf(e3.y);
    a1[6] = (short)f2bf(e3.z); a1[7] = (short)f2bf(e3.w);

    for (int h = 0; h < H; ++h) {
        f32x4 acc[5];
#pragma unroll
        for (int nt = 0; nt < 5; ++nt) {
            acc[nt] = (f32x4)(0.f);
            const unsigned short* wp = Wt + (((size_t)h * 80 + nt * 16 + r) * 64 + grp * 8);
            bf16x8 b0 = *(const bf16x8*)wp;        // same k mapping as A
            bf16x8 b1 = *(const bf16x8*)(wp + 32);
            acc[nt] = __builtin_amdgcn_mfma_f32_16x16x32_bf16(a0, b0, acc[nt], 0, 0, 0);
            acc[nt] = __builtin_amdgcn_mfma_f32_16x16x32_bf16(a1, b1, acc[nt], 0, 0, 0);
        }
        // C/D layout: col = nt*16 + r, row(u-offset) = grp*4 + j
#pragma unroll
        for (int j = 0; j < 4; ++j) {
            const long u = u0 + grp * 4 + j;
            if (u < U) {
#pragma unroll
                for (int nt = 0; nt < 4; ++nt)
                    WhB[((size_t)h * U + u) * 64 + nt * 16 + r] = f2bf(acc[nt][j]);
                if (r < 4) scf[(((size_t)h * U + u) << 2) + r] = acc[4][j];
            }
        }
    }
}

// Kernel 2: one wave per (row, head); blocks pinned so head h lives on XCDs {2h,2h+1}
// (head slab = 6.4MB WhB + 0.8MB scores ~ fits the pair's 8MB L2).
// Inner loop: 2 edges per iteration, one dword load per lane (dims 2m,2m+1).
template <int DP, int DN>
__global__ __launch_bounds__(256) void agg_kernel(
    const int* __restrict__ row_unique,
    const int* __restrict__ pos_col, const int* __restrict__ neg_col,
    const unsigned short* __restrict__ WhB, const float4* __restrict__ sc,
    float* __restrict__ out, int N, int U, int rDP, int rDN, int H, int pinned)
{
    const int DEGP = DP > 0 ? DP : rDP;
    const int DEGN = DN > 0 ? DN : rDN;
    const int NE   = DEGP + 1 + DEGN;       // 33
    const int NEP  = (NE + 1) & ~1;         // 34

    const int wave = threadIdx.x >> 6;
    const int lane = threadIdx.x & 63;

    __shared__ int2 s_pair[4][40];          // wave-private {col, att} slices

    int i, h;
    if (pinned) {
        const int xcd = blockIdx.x & 7;
        h = xcd >> 1;
        const int rg = ((blockIdx.x >> 3) << 1) | (blockIdx.x & 1);
        i = rg * 4 + wave;
    } else {
        const long j = (long)blockIdx.x * 4 + wave;
        i = (int)(j % N);
        h = (int)(j / N);
        if (h >= H) return;
    }
    if (i >= N) return;

    const float4* sch = sc + (size_t)h * U;
    const float4 scd = sch[row_unique[i]];   // .x = pos_dst, .z = neg_dst

    int col = 0;
    float score = -INFINITY;
    if (lane < NE) {
        if (lane < DEGP)       col = pos_col[(size_t)i * DEGP + lane];
        else if (lane == DEGP) col = pos_col[(size_t)N * DEGP + i];  // self edge
        else                   col = neg_col[(size_t)i * DEGN + (lane - DEGP - 1)];
        const float4 scs = sch[col];         // .y = pos_src, .w = neg_src
        const float raw = (lane <= DEGP) ? (scd.x + scs.y) : (scd.z + scs.w);
        score = (raw > 0.f) ? raw : LRELU_ALPHA * raw;
    }
    float m = score;
#pragma unroll
    for (int off = 32; off; off >>= 1) m = fmaxf(m, __shfl_xor(m, off, 64));
    const float ex = (lane < NE) ? __expf(score - m) : 0.f;
    float ssum = ex;
#pragma unroll
    for (int off = 32; off; off >>= 1) ssum += __shfl_xor(ssum, off, 64);
    const float att = ex / ssum;

    if (lane < NEP)
        s_pair[wave][lane] = make_int2((lane < NE) ? col : 0,
                                       __float_as_int((lane < NE) ? att : 0.f));
    // wave-private LDS slice: no barrier needed (compiler orders via lgkmcnt)

    const unsigned int* wh2 = (const unsigned int*)(WhB + (size_t)h * U * 64);
    const int mlo  = lane & 31;    // dim pair index
    const int half = lane >> 5;    // 0: even edges, 1: odd edges
    float acc0 = 0.f, acc1 = 0.f;
#pragma unroll
    for (int it = 0; it < NEP / 2; ++it) {
        const int2 p = s_pair[wave][2 * it + half];
        const unsigned v = wh2[(size_t)(unsigned)p.x * 32 + mlo];
        const float a = __int_as_float(p.y);
        union { unsigned u; float f; } lo, hi;
        lo.u = v << 16;
        hi.u = v & 0xffff0000u;
        acc0 = fmaf(a, lo.f, acc0);
        acc1 = fmaf(a, hi.f, acc1);
    }
    acc0 += __shfl_xor(acc0, 32, 64);
    acc1 += __shfl_xor(acc1, 32, 64);
    if (lane < 32) {
        float2 o;
        o.x = fmaxf(acc0, 0.f);
        o.y = fmaxf(acc1, 0.f);
        *(float2*)(out + (size_t)i * (H * 64) + h * 64 + 2 * mlo) = o;
    }
}

extern "C" void kernel_launch(void* const* d_in, const int* in_sizes, int n_in,
                              void* d_out, int out_size, void* d_ws, size_t ws_size,
                              hipStream_t stream) {
    const float* nf     = (const float*)d_in[0];
    const float* W      = (const float*)d_in[1];
    const float* a_pos  = (const float*)d_in[2];
    const float* a_neg  = (const float*)d_in[3];
    const float* ee     = (const float*)d_in[4];
    const float* et     = (const float*)d_in[5];
    const int* unique_nodes = (const int*)d_in[6];
    const int* row_unique   = (const int*)d_in[7];
    const int* pos_col  = (const int*)d_in[9];
    const int* neg_col  = (const int*)d_in[11];

    const int U    = in_sizes[6];
    const int N    = in_sizes[7];
    const int Epos = in_sizes[8];
    const int Eneg = in_sizes[10];
    const int H    = in_sizes[1] / (64 * 64);   // W is [H,64,64]
    const int DEGN = Eneg / N;                  // 16
    const int DEGP = Epos / N - 1;              // 16 (self edges appended)
    const int ET   = in_sizes[4] / 64;          // 32 edge types

    unsigned short* WhB = (unsigned short*)d_ws;
    const size_t whBytes = (((size_t)H * U * 64 * sizeof(unsigned short)) + 255) & ~(size_t)255;
    float* scf = (float*)((char*)d_ws + whBytes);
    const size_t scBytes = (((size_t)H * U * 4 * sizeof(float)) + 255) & ~(size_t)255;
    unsigned short* Wt = (unsigned short*)((char*)d_ws + whBytes + scBytes);
    const float4* sc = (const float4*)scf;
    float* out = (float*)d_out;

    const int PT = H * 80 * 64 + ET * 64;
    prep_kernel<<<(PT + 255) / 256, 256, 0, stream>>>(W, a_pos, a_neg, ee, et, Wt,
                                                      out + (size_t)N * H * 64, H, ET);

    const int nwaves = (U + 15) / 16;
    wh_mfma_kernel<<<(nwaves + 3) / 4, 256, 0, stream>>>(nf, Wt, unique_nodes, WhB, scf, U, H);

    const long NBp = (long)N * H / 4;
    const int pinned = (H == 4 && (N % 4) == 0 && (NBp % 8) == 0) ? 1 : 0;
    const long NB = pinned ? NBp : ((long)N * H + 3) / 4;
    if (DEGP == 16 && DEGN == 16)
        agg_kernel<16, 16><<<NB, 256, 0, stream>>>(row_unique, pos_col, neg_col, WhB, sc,
                                                   out, N, U, DEGP, DEGN, H, pinned);
    else
        agg_kernel<0, 0><<<NB, 256, 0, stream>>>(row_unique, pos_col, neg_col, WhB, sc,
                                                 out, N, U, DEGP, DEGN, H, pinned);
}